// Round 1
// baseline (688.577 us; speedup 1.0000x reference)
//
#include <hip/hip_runtime.h>

#define N_DET 4096
#define NW 64               // 4096 bits = 64 u64 words
#define IOU_TR 0.3f
#define SCORE_TR 0.1f
#define EPS 1e-9f

// ---------------------------------------------------------------------------
// ws layout (bytes):
//   rows   : 4096*8 f32   @ 0        (sorted detection rows)       128 KB
//   soa    : 7*4096 f32   @ 131072   (lox,loy,loz,hix,hiy,hiz,vol) 112 KB
//   valid  : 64 u64       @ 245760
//   keep   : 64 u64       @ 246272
//   sup    : 4096*64 u64  @ 246784   (suppression bitmatrix)         2 MB
// total ~2.29 MB
// ---------------------------------------------------------------------------

__device__ inline unsigned long long shfl64(unsigned long long v, int src) {
    int lo = __shfl((int)(unsigned)(v & 0xffffffffull), src, 64);
    int hi = __shfl((int)(unsigned)(v >> 32), src, 64);
    return ((unsigned long long)(unsigned)hi << 32) | (unsigned)lo;
}

// K1: stable descending sort by rank-counting + scatter rows & box SoA.
__global__ void k_sort(const float* __restrict__ res, float* __restrict__ rows,
                       float* __restrict__ soa) {
    __shared__ float s_scores[N_DET];
    int tid = threadIdx.x;
    int gid = blockIdx.x * 256 + tid;
    for (int j = tid; j < N_DET; j += 256) s_scores[j] = res[j * 8];
    __syncthreads();
    float s = s_scores[gid];
    int rank = 0;
    for (int j = 0; j < N_DET; ++j) {
        float sj = s_scores[j];
        rank += (sj > s) || (sj == s && j < gid);
    }
    float4 a = *(const float4*)(res + gid * 8);
    float4 b = *(const float4*)(res + gid * 8 + 4);
    *(float4*)(rows + rank * 8)     = a;
    *(float4*)(rows + rank * 8 + 4) = b;
    // a = (score, class, cx, cy); b = (cz, dx, dy, dz)
    float cx = a.z, cy = a.w, cz = b.x, dx = b.y, dy = b.z, dz = b.w;
    soa[0 * N_DET + rank] = cx - dx * 0.5f;
    soa[1 * N_DET + rank] = cy - dy * 0.5f;
    soa[2 * N_DET + rank] = cz - dz * 0.5f;
    soa[3 * N_DET + rank] = cx + dx * 0.5f;
    soa[4 * N_DET + rank] = cy + dy * 0.5f;
    soa[5 * N_DET + rank] = cz + dz * 0.5f;
    soa[6 * N_DET + rank] = (dx * dy) * dz;   // np.prod order: ((dx*dy)*dz)
}

// K2: validity ballot over sorted scores -> 64 words.
__global__ void k_valid(const float* __restrict__ rows,
                        unsigned long long* __restrict__ valid) {
    int gid = blockIdx.x * 64 + threadIdx.x;
    bool v = rows[gid * 8] >= SCORE_TR;
    unsigned long long m = __ballot(v);
    if (threadIdx.x == 0) valid[blockIdx.x] = m;
}

// K3: suppression bitmatrix. One wave per row i; 64 ballots of 64 lanes.
__global__ void k_sup(const float* __restrict__ soa,
                      unsigned long long* __restrict__ sup) {
    int lane = threadIdx.x & 63;
    int wave = threadIdx.x >> 6;
    int i = blockIdx.x * 4 + wave;
    float ilox = soa[0 * N_DET + i], iloy = soa[1 * N_DET + i], iloz = soa[2 * N_DET + i];
    float ihix = soa[3 * N_DET + i], ihiy = soa[4 * N_DET + i], ihiz = soa[5 * N_DET + i];
    float ivol = soa[6 * N_DET + i];
    for (int w = 0; w < NW; ++w) {
        int j = w * 64 + lane;
        float lox = soa[0 * N_DET + j], loy = soa[1 * N_DET + j], loz = soa[2 * N_DET + j];
        float hix = soa[3 * N_DET + j], hiy = soa[4 * N_DET + j], hiz = soa[5 * N_DET + j];
        float vol = soa[6 * N_DET + j];
        float ix = fminf(ihix, hix) - fmaxf(ilox, lox); ix = fmaxf(ix, 0.0f);
        float iy = fminf(ihiy, hiy) - fmaxf(iloy, loy); iy = fmaxf(iy, 0.0f);
        float iz = fminf(ihiz, hiz) - fmaxf(iloz, loz); iz = fmaxf(iz, 0.0f);
        float inter = (ix * iy) * iz;                 // ((x*y)*z) like np.prod
        float uni = ivol + vol - inter;               // (vol_i+vol_j)-inter
        float iou = inter / (uni + EPS);              // IEEE div (HIP default CR)
        bool sb = (iou > IOU_TR) && (j > i);
        unsigned long long m = __ballot(sb);
        if (lane == 0) sup[(size_t)i * NW + w] = m;
    }
}

// K4: serial greedy scan. ONE wave. Lane l holds active-word l in a register.
// Every lane mirrors the current word `aw` uniformly so the per-bit critical
// path is pure in-register ALU (no shuffle); shuffle only at word boundaries.
// Suppression rows are prefetched depth-4 in 8-bit chunks (static indexing).
__global__ void k_scan(const unsigned long long* __restrict__ sup,
                       const unsigned long long* __restrict__ valid,
                       unsigned long long* __restrict__ keep) {
    const int lane = threadIdx.x;
    unsigned long long act = valid[lane];
    unsigned long long aw = 0, kept = 0;

    constexpr int CH = 8;                 // bits per chunk
    constexpr int D = 4;                  // prefetch depth (chunks)
    constexpr int NCHUNK = N_DET / CH;    // 512

    unsigned long long fw[D][CH];         // sup[i][lane]
    unsigned long long fd[D][CH];         // sup[i][i>>6] (uniform)

#pragma unroll
    for (int d = 0; d < D; ++d) {
#pragma unroll
        for (int k = 0; k < CH; ++k) {
            int i = d * CH + k;
            fw[d][k] = sup[(size_t)i * NW + lane];
            fd[d][k] = sup[(size_t)i * NW + (i >> 6)];
        }
    }

    for (int cb = 0; cb < NCHUNK; cb += D) {
#pragma unroll
        for (int d = 0; d < D; ++d) {
            int c = cb + d;
#pragma unroll
            for (int k = 0; k < CH; ++k) {
                int i = c * CH + k;
                int w = i >> 6;
                int b = i & 63;
                if (b == 0) {             // word boundary: refresh mirror
                    aw = shfl64(act, w);
                    kept = 0ull;
                }
                unsigned long long cur = (aw >> b) & 1ull;
                unsigned long long m = 0ull - cur;        // 0 or ~0
                aw  &= ~(fd[d][k] & m);
                act &= ~(fw[d][k] & m);
                kept |= cur << b;
                if (b == 63 && lane == 0) keep[w] = kept;
            }
            int cn = c + D;
            if (cn < NCHUNK) {
#pragma unroll
                for (int k = 0; k < CH; ++k) {
                    int i = cn * CH + k;
                    fw[d][k] = sup[(size_t)i * NW + lane];
                    fd[d][k] = sup[(size_t)i * NW + (i >> 6)];
                }
            }
        }
    }
}

// K5: gate rows by keep mask.
__global__ void k_out(const float* __restrict__ rows,
                      const unsigned long long* __restrict__ keep,
                      float* __restrict__ out) {
    int i = blockIdx.x * 256 + threadIdx.x;   // one detection per thread
    bool kp = (keep[i >> 6] >> (i & 63)) & 1ull;
    float4 a = kp ? ((const float4*)rows)[i * 2]     : make_float4(0.f, 0.f, 0.f, 0.f);
    float4 b = kp ? ((const float4*)rows)[i * 2 + 1] : make_float4(0.f, 0.f, 0.f, 0.f);
    ((float4*)out)[i * 2]     = a;
    ((float4*)out)[i * 2 + 1] = b;
}

extern "C" void kernel_launch(void* const* d_in, const int* in_sizes, int n_in,
                              void* d_out, int out_size, void* d_ws, size_t ws_size,
                              hipStream_t stream) {
    const float* res = (const float*)d_in[0];
    float* out = (float*)d_out;

    float* rows = (float*)d_ws;                       // 32768 f32
    float* soa  = rows + N_DET * 8;                   // 28672 f32
    unsigned long long* valid = (unsigned long long*)(soa + 7 * N_DET);
    unsigned long long* keep  = valid + NW;
    unsigned long long* sup   = keep + NW;            // 4096*64 u64

    k_sort <<<N_DET / 256, 256, 0, stream>>>(res, rows, soa);
    k_valid<<<NW, 64, 0, stream>>>(rows, valid);
    k_sup  <<<N_DET / 4, 256, 0, stream>>>(soa, sup);
    k_scan <<<1, 64, 0, stream>>>(sup, valid, keep);
    k_out  <<<N_DET / 256, 256, 0, stream>>>(rows, keep, out);
}

// Round 2
// 385.068 us; speedup vs baseline: 1.7882x; 1.7882x over previous
//
#include <hip/hip_runtime.h>

#define N_DET 4096
#define NW 64               // 4096 bits = 64 u64 words
#define IOU_TR 0.3f
#define SCORE_TR 0.1f
#define EPS 1e-9f

// ---------------------------------------------------------------------------
// ws layout:
//   rows   : 4096*8 f32   (sorted detection rows)       128 KB
//   soa    : 7*4096 f32   (lox,loy,loz,hix,hiy,hiz,vol) 112 KB
//   valid  : 64 u64
//   keep   : 64 u64
//   sup    : 4096*64 u64  (suppression bitmatrix)         2 MB
// ---------------------------------------------------------------------------

// K1: stable descending sort by rank-counting + scatter rows & box SoA.
__global__ void k_sort(const float* __restrict__ res, float* __restrict__ rows,
                       float* __restrict__ soa) {
    __shared__ float s_scores[N_DET];
    int tid = threadIdx.x;
    int gid = blockIdx.x * 256 + tid;
    for (int j = tid; j < N_DET; j += 256) s_scores[j] = res[j * 8];
    __syncthreads();
    float s = s_scores[gid];
    int rank = 0;
    for (int j = 0; j < N_DET; ++j) {
        float sj = s_scores[j];
        rank += (sj > s) || (sj == s && j < gid);
    }
    float4 a = *(const float4*)(res + gid * 8);
    float4 b = *(const float4*)(res + gid * 8 + 4);
    *(float4*)(rows + rank * 8)     = a;
    *(float4*)(rows + rank * 8 + 4) = b;
    // a = (score, class, cx, cy); b = (cz, dx, dy, dz)
    float cx = a.z, cy = a.w, cz = b.x, dx = b.y, dy = b.z, dz = b.w;
    soa[0 * N_DET + rank] = cx - dx * 0.5f;
    soa[1 * N_DET + rank] = cy - dy * 0.5f;
    soa[2 * N_DET + rank] = cz - dz * 0.5f;
    soa[3 * N_DET + rank] = cx + dx * 0.5f;
    soa[4 * N_DET + rank] = cy + dy * 0.5f;
    soa[5 * N_DET + rank] = cz + dz * 0.5f;
    soa[6 * N_DET + rank] = (dx * dy) * dz;   // np.prod order: ((dx*dy)*dz)
}

// K2: validity ballot over sorted scores -> 64 words.
__global__ void k_valid(const float* __restrict__ rows,
                        unsigned long long* __restrict__ valid) {
    int gid = blockIdx.x * 64 + threadIdx.x;
    bool v = rows[gid * 8] >= SCORE_TR;
    unsigned long long m = __ballot(v);
    if (threadIdx.x == 0) valid[blockIdx.x] = m;
}

// K3: suppression bitmatrix. One wave per row i; 64 ballots of 64 lanes.
__global__ void k_sup(const float* __restrict__ soa,
                      unsigned long long* __restrict__ sup) {
    int lane = threadIdx.x & 63;
    int wave = threadIdx.x >> 6;
    int i = blockIdx.x * 4 + wave;
    float ilox = soa[0 * N_DET + i], iloy = soa[1 * N_DET + i], iloz = soa[2 * N_DET + i];
    float ihix = soa[3 * N_DET + i], ihiy = soa[4 * N_DET + i], ihiz = soa[5 * N_DET + i];
    float ivol = soa[6 * N_DET + i];
    for (int w = 0; w < NW; ++w) {
        int j = w * 64 + lane;
        float lox = soa[0 * N_DET + j], loy = soa[1 * N_DET + j], loz = soa[2 * N_DET + j];
        float hix = soa[3 * N_DET + j], hiy = soa[4 * N_DET + j], hiz = soa[5 * N_DET + j];
        float vol = soa[6 * N_DET + j];
        float ix = fminf(ihix, hix) - fmaxf(ilox, lox); ix = fmaxf(ix, 0.0f);
        float iy = fminf(ihiy, hiy) - fmaxf(iloy, loy); iy = fmaxf(iy, 0.0f);
        float iz = fminf(ihiz, hiz) - fmaxf(iloz, loz); iz = fmaxf(iz, 0.0f);
        float inter = (ix * iy) * iz;                 // ((x*y)*z) like np.prod
        float uni = ivol + vol - inter;               // (vol_i+vol_j)-inter
        float iou = inter / (uni + EPS);              // IEEE div (HIP default CR)
        bool sb = (iou > IOU_TR) && (j > i);
        unsigned long long m = __ballot(sb);
        if (lane == 0) sup[(size_t)i * NW + w] = m;
    }
}

// K4: serial greedy scan. ONE wave, one active-word per lane (in register).
// cur-bit extraction via ballot -> SGPR scalar ops (no shuffles, no diag load).
// Row words live in a 64-entry register buffer (128 VGPRs); each slot is
// consumed then immediately refilled with the next word's row -> ~64-row
// prefetch distance, all addresses static. __launch_bounds__(64,1) so the
// compiler can use the whole VGPR file (round-1 failure: arrays spilled to
// scratch at the default 64-VGPR budget -> 290 cyc/bit).
__global__ void __launch_bounds__(64, 1)
k_scan(const unsigned long long* __restrict__ sup,
       const unsigned long long* __restrict__ valid,
       unsigned long long* __restrict__ keep) {
    const int lane = threadIdx.x;
    unsigned long long act = valid[lane];
    unsigned long long keepword = 0;
    unsigned long long buf[64];

#pragma unroll
    for (int k = 0; k < 64; ++k)
        buf[k] = sup[(size_t)k * NW + lane];

    for (int w = 0; w < NW; ++w) {
        unsigned long long kept = 0;
        const bool pf = (w + 1) < NW;
        const unsigned long long* nxt = sup + ((size_t)(w + 1) * 64) * NW + lane;
#pragma unroll
        for (int k = 0; k < 64; ++k) {
            unsigned long long rowm = buf[k];
            if (pf) buf[k] = nxt[(size_t)k * NW];     // refill slot for word w+1
            unsigned long long ball = __ballot((act & (1ull << k)) != 0ull);
            unsigned long long cur = (ball >> w) & 1ull;   // bit i of act (scalar)
            unsigned long long m = 0ull - cur;             // 0 or ~0 (scalar)
            act &= ~(rowm & m);
            kept |= cur << k;
        }
        keepword = (lane == w) ? kept : keepword;
    }
    keep[lane] = keepword;
}

// K5: gate rows by keep mask.
__global__ void k_out(const float* __restrict__ rows,
                      const unsigned long long* __restrict__ keep,
                      float* __restrict__ out) {
    int i = blockIdx.x * 256 + threadIdx.x;   // one detection per thread
    bool kp = (keep[i >> 6] >> (i & 63)) & 1ull;
    float4 a = kp ? ((const float4*)rows)[i * 2]     : make_float4(0.f, 0.f, 0.f, 0.f);
    float4 b = kp ? ((const float4*)rows)[i * 2 + 1] : make_float4(0.f, 0.f, 0.f, 0.f);
    ((float4*)out)[i * 2]     = a;
    ((float4*)out)[i * 2 + 1] = b;
}

extern "C" void kernel_launch(void* const* d_in, const int* in_sizes, int n_in,
                              void* d_out, int out_size, void* d_ws, size_t ws_size,
                              hipStream_t stream) {
    const float* res = (const float*)d_in[0];
    float* out = (float*)d_out;

    float* rows = (float*)d_ws;                       // 32768 f32
    float* soa  = rows + N_DET * 8;                   // 28672 f32
    unsigned long long* valid = (unsigned long long*)(soa + 7 * N_DET);
    unsigned long long* keep  = valid + NW;
    unsigned long long* sup   = keep + NW;            // 4096*64 u64

    k_sort <<<N_DET / 256, 256, 0, stream>>>(res, rows, soa);
    k_valid<<<NW, 64, 0, stream>>>(rows, valid);
    k_sup  <<<N_DET / 4, 256, 0, stream>>>(soa, sup);
    k_scan <<<1, 64, 0, stream>>>(sup, valid, keep);
    k_out  <<<N_DET / 256, 256, 0, stream>>>(rows, keep, out);
}

// Round 3
// 302.782 us; speedup vs baseline: 2.2742x; 1.2718x over previous
//
#include <hip/hip_runtime.h>

typedef unsigned long long u64;

#define N_DET 4096
#define NW 64               // 4096 bits = 64 u64 words
#define IOU_TR 0.3f
#define SCORE_TR 0.1f
#define EPS 1e-9f

// ---------------------------------------------------------------------------
// ws layout:
//   rows   : 4096*8 f32   (sorted detection rows)            128 KB
//   soa    : 7*4096 f32   (lox,loy,loz,hix,hiy,hiz,vol)      112 KB
//   valid  : 64 u64
//   keep   : 64 u64
//   T      : 64*4096 u64  (TRANSPOSED sup bitmatrix: T[w][i])  2 MB
// T[w*4096+i] = word w of suppression row i (bits j in [64w,64w+64), j>i only)
// ---------------------------------------------------------------------------

// K1: stable descending sort by rank-counting + scatter rows & box SoA.
__global__ void k_sort(const float* __restrict__ res, float* __restrict__ rows,
                       float* __restrict__ soa) {
    __shared__ float s_scores[N_DET];
    int tid = threadIdx.x;
    int gid = blockIdx.x * 256 + tid;
    for (int j = tid; j < N_DET; j += 256) s_scores[j] = res[j * 8];
    __syncthreads();
    float s = s_scores[gid];
    int rank = 0;
    for (int j = 0; j < N_DET; ++j) {
        float sj = s_scores[j];
        rank += (sj > s) || (sj == s && j < gid);
    }
    float4 a = *(const float4*)(res + gid * 8);
    float4 b = *(const float4*)(res + gid * 8 + 4);
    *(float4*)(rows + rank * 8)     = a;
    *(float4*)(rows + rank * 8 + 4) = b;
    // a = (score, class, cx, cy); b = (cz, dx, dy, dz)
    float cx = a.z, cy = a.w, cz = b.x, dx = b.y, dy = b.z, dz = b.w;
    soa[0 * N_DET + rank] = cx - dx * 0.5f;
    soa[1 * N_DET + rank] = cy - dy * 0.5f;
    soa[2 * N_DET + rank] = cz - dz * 0.5f;
    soa[3 * N_DET + rank] = cx + dx * 0.5f;
    soa[4 * N_DET + rank] = cy + dy * 0.5f;
    soa[5 * N_DET + rank] = cz + dz * 0.5f;
    soa[6 * N_DET + rank] = (dx * dy) * dz;   // np.prod order: ((dx*dy)*dz)
}

// K2: validity ballot over sorted scores -> 64 words.
__global__ void k_valid(const float* __restrict__ rows,
                        u64* __restrict__ valid) {
    int gid = blockIdx.x * 64 + threadIdx.x;
    bool v = rows[gid * 8] >= SCORE_TR;
    u64 m = __ballot(v);
    if (threadIdx.x == 0) valid[blockIdx.x] = m;
}

// K3: suppression bitmatrix (transposed). One wave per row i; 64 ballots.
__global__ void k_sup(const float* __restrict__ soa,
                      u64* __restrict__ T) {
    int lane = threadIdx.x & 63;
    int wave = threadIdx.x >> 6;
    int i = blockIdx.x * 4 + wave;
    float ilox = soa[0 * N_DET + i], iloy = soa[1 * N_DET + i], iloz = soa[2 * N_DET + i];
    float ihix = soa[3 * N_DET + i], ihiy = soa[4 * N_DET + i], ihiz = soa[5 * N_DET + i];
    float ivol = soa[6 * N_DET + i];
    for (int w = 0; w < NW; ++w) {
        int j = w * 64 + lane;
        float lox = soa[0 * N_DET + j], loy = soa[1 * N_DET + j], loz = soa[2 * N_DET + j];
        float hix = soa[3 * N_DET + j], hiy = soa[4 * N_DET + j], hiz = soa[5 * N_DET + j];
        float vol = soa[6 * N_DET + j];
        float ix = fminf(ihix, hix) - fmaxf(ilox, lox); ix = fmaxf(ix, 0.0f);
        float iy = fminf(ihiy, hiy) - fmaxf(iloy, loy); iy = fmaxf(iy, 0.0f);
        float iz = fminf(ihiz, hiz) - fmaxf(iloz, loz); iz = fmaxf(iz, 0.0f);
        float inter = (ix * iy) * iz;                 // ((x*y)*z) like np.prod
        float uni = ivol + vol - inter;               // (vol_i+vol_j)-inter
        float iou = inter / (uni + EPS);              // IEEE div (HIP default CR)
        bool sb = (iou > IOU_TR) && (j > i);
        u64 m = __ballot(sb);
        if (lane == 0) T[(size_t)w * N_DET + i] = m;
    }
}

// K4: serial greedy scan. ONE wave; lane l holds active-word l in a register
// and streams T[l][i] (contiguous per lane) through 32 NAMED ulonglong4
// registers (no arrays -> no scratch; round-1/2 failure mode eliminated).
// Final act == keep mask (rows only contain bits j>i, so bit i is frozen
// after step i).
#define STEP(RW, W, K) {                                                     \
    u64 ball = __ballot(((long long)(act << (63 - (K)))) < 0);               \
    u64 m = (u64)(((long long)(ball << (63 - (W)))) >> 63);                  \
    act &= ~((RW) & m); }

#define QUAD(Q, RS, J, W) {                                                  \
    ulonglong4 q_ = (Q); (Q) = (RS)[(J)];                                    \
    STEP(q_.x, W, 4*(J)+0) STEP(q_.y, W, 4*(J)+1)                            \
    STEP(q_.z, W, 4*(J)+2) STEP(q_.w, W, 4*(J)+3) }

#define WORDX(P, RS, W)                                                      \
    QUAD(P##0,RS,0,W)  QUAD(P##1,RS,1,W)  QUAD(P##2,RS,2,W)  QUAD(P##3,RS,3,W) \
    QUAD(P##4,RS,4,W)  QUAD(P##5,RS,5,W)  QUAD(P##6,RS,6,W)  QUAD(P##7,RS,7,W) \
    QUAD(P##8,RS,8,W)  QUAD(P##9,RS,9,W)  QUAD(P##10,RS,10,W) QUAD(P##11,RS,11,W) \
    QUAD(P##12,RS,12,W) QUAD(P##13,RS,13,W) QUAD(P##14,RS,14,W) QUAD(P##15,RS,15,W)

__global__ void __launch_bounds__(64, 1)
k_scan(const u64* __restrict__ T, const u64* __restrict__ valid,
       u64* __restrict__ keep) {
    const int lane = threadIdx.x;
    const ulonglong4* p4 = (const ulonglong4*)(T + (size_t)lane * N_DET);
    u64 act = valid[lane];

    // prefill: a = word 0 rows, b = word 1 rows
    ulonglong4 a0 = p4[0],  a1 = p4[1],  a2 = p4[2],  a3 = p4[3],
               a4 = p4[4],  a5 = p4[5],  a6 = p4[6],  a7 = p4[7],
               a8 = p4[8],  a9 = p4[9],  a10 = p4[10], a11 = p4[11],
               a12 = p4[12], a13 = p4[13], a14 = p4[14], a15 = p4[15];
    ulonglong4 b0 = p4[16], b1 = p4[17], b2 = p4[18], b3 = p4[19],
               b4 = p4[20], b5 = p4[21], b6 = p4[22], b7 = p4[23],
               b8 = p4[24], b9 = p4[25], b10 = p4[26], b11 = p4[27],
               b12 = p4[28], b13 = p4[29], b14 = p4[30], b15 = p4[31];

    for (int t = 0; t < 32; ++t) {
        const int w0 = 2 * t, w1 = 2 * t + 1;
        // refill sources (clamped to word 0 on the tail; values unused)
        const ulonglong4* ra = p4 + (size_t)((w0 + 2 < NW) ? (w0 + 2) : 0) * 16;
        const ulonglong4* rb = p4 + (size_t)((w1 + 2 < NW) ? (w1 + 2) : 0) * 16;
        WORDX(a, ra, w0)
        WORDX(b, rb, w1)
    }
    keep[lane] = act;
}

// K5: gate rows by keep mask.
__global__ void k_out(const float* __restrict__ rows,
                      const u64* __restrict__ keep,
                      float* __restrict__ out) {
    int i = blockIdx.x * 256 + threadIdx.x;   // one detection per thread
    bool kp = (keep[i >> 6] >> (i & 63)) & 1ull;
    float4 a = kp ? ((const float4*)rows)[i * 2]     : make_float4(0.f, 0.f, 0.f, 0.f);
    float4 b = kp ? ((const float4*)rows)[i * 2 + 1] : make_float4(0.f, 0.f, 0.f, 0.f);
    ((float4*)out)[i * 2]     = a;
    ((float4*)out)[i * 2 + 1] = b;
}

extern "C" void kernel_launch(void* const* d_in, const int* in_sizes, int n_in,
                              void* d_out, int out_size, void* d_ws, size_t ws_size,
                              hipStream_t stream) {
    const float* res = (const float*)d_in[0];
    float* out = (float*)d_out;

    float* rows = (float*)d_ws;                       // 32768 f32
    float* soa  = rows + N_DET * 8;                   // 28672 f32
    u64* valid = (u64*)(soa + 7 * N_DET);
    u64* keep  = valid + NW;
    u64* T     = keep + NW;                           // 64*4096 u64 (transposed)

    k_sort <<<N_DET / 256, 256, 0, stream>>>(res, rows, soa);
    k_valid<<<NW, 64, 0, stream>>>(rows, valid);
    k_sup  <<<N_DET / 4, 256, 0, stream>>>(soa, T);
    k_scan <<<1, 64, 0, stream>>>(T, valid, keep);
    k_out  <<<N_DET / 256, 256, 0, stream>>>(rows, keep, out);
}